// Round 1
// baseline (5110.236 us; speedup 1.0000x reference)
//
#include <hip/hip_runtime.h>
#include <hip/hip_bf16.h>
#include <math.h>

// FlashSVDRoPEAttention — fp32 baseline (round 1)
// B=4 H=16 M=2048 R=32 DH=64. Two phases:
//   1) qkv_rope_kernel: Q/K/V = P·V + b, RoPE(Q,K), scale folded into Q.
//      Layout (B,H,M,DH) fp32 in d_ws (3 x 33.55MB = 100.7MB).
//   2) flash_fp32_kernel: causal flash attention, 64x64 tiles, 4x4 register
//      blocking, online softmax. Output (B,M,H,DH) fp32.

#define B_ 4
#define H_ 16
#define M_ 2048
#define R_ 32
#define DH_ 64
#define SCALE 0.125f          // 1/sqrt(64)
#define NEGV -1.0e30f

typedef float f32x4 __attribute__((ext_vector_type(4)));

// ---------------------------------------------------------------------------
// Phase 1: projection + RoPE. One wave (64 lanes) per (b,h,m) row; lane = d.
// ---------------------------------------------------------------------------
__global__ __launch_bounds__(256) void qkv_rope_kernel(
    const float* __restrict__ Pq, const float* __restrict__ Pk,
    const float* __restrict__ Pv,
    const float* __restrict__ Vq, const float* __restrict__ Vk,
    const float* __restrict__ Vv,
    const float* __restrict__ bq, const float* __restrict__ bk,
    const float* __restrict__ bv,
    const int* __restrict__ pos_ids,
    float* __restrict__ Qr, float* __restrict__ Kr, float* __restrict__ Vo)
{
    const int wid  = (blockIdx.x << 2) + (threadIdx.x >> 6); // row id ((b*H+h)*M+m)
    const int lane = threadIdx.x & 63;                        // d
    const int total = B_ * H_ * M_;
    if (wid >= total) return;

    const int m  = wid % M_;
    const int bh = wid / M_;
    const int h  = bh % H_;
    const int b  = bh / H_;

    // each half-wave loads the 32-float P row; broadcast via shfl
    const float pq = Pq[(size_t)wid * R_ + (lane & 31)];
    const float pk = Pk[(size_t)wid * R_ + (lane & 31)];
    const float pv = Pv[(size_t)wid * R_ + (lane & 31)];

    const float* __restrict__ vq = Vq + (size_t)h * R_ * DH_ + lane;
    const float* __restrict__ vk = Vk + (size_t)h * R_ * DH_ + lane;
    const float* __restrict__ vv = Vv + (size_t)h * R_ * DH_ + lane;

    float q = 0.f, k = 0.f, v = 0.f;
    #pragma unroll
    for (int r = 0; r < R_; ++r) {
        const float aq = __shfl(pq, r);
        const float ak = __shfl(pk, r);
        const float av = __shfl(pv, r);
        q += aq * vq[r * DH_];
        k += ak * vk[r * DH_];
        v += av * vv[r * DH_];
    }
    q += bq[h * DH_ + lane];
    k += bk[h * DH_ + lane];
    v += bv[h * DH_ + lane];

    // RoPE: out[d<32] = x[d]*c - x[d+32]*s ; out[d>=32] = x[d-32]*s + x[d]*c
    // freq index = (d&31)>>1  (repeat-then-slice quirk of the reference)
    const int   j    = lane & 31;
    const float ex   = (float)(j >> 1) / 32.0f;
    const float freq = powf((float)10000.0f, -ex);
    const int   pos  = pos_ids[b * M_ + m];
    const float ang  = (float)pos * freq;
    float s_, c_;
    sincosf(ang, &s_, &c_);

    const float qp = __shfl_xor(q, 32);   // partner element x[d^32]
    const float kp = __shfl_xor(k, 32);
    const float qr = (lane < 32) ? (q * c_ - qp * s_) : (qp * s_ + q * c_);
    const float kr = (lane < 32) ? (k * c_ - kp * s_) : (kp * s_ + k * c_);

    const size_t o = (size_t)wid * DH_ + lane;
    Qr[o] = qr * SCALE;   // fold softmax scale into Q
    Kr[o] = kr;
    Vo[o] = v;
}

// ---------------------------------------------------------------------------
// Phase 2: causal flash attention, fp32 vector ALU.
// Block = 256 threads, 64x64 Q-tile. Thread t: tr=t>>4 (row group), tc=t&15.
// S ownership: rows tr*4+i, cols tc+16j (conflict-minimal K reads).
// O ownership: rows tr*4+i, cols tc*4+j (contiguous -> float4 stores).
// P round-trips through the Ks LDS buffer (reused after S is consumed).
// ---------------------------------------------------------------------------
__global__ __launch_bounds__(256) void flash_fp32_kernel(
    const float* __restrict__ Q, const float* __restrict__ K,
    const float* __restrict__ V, const int* __restrict__ amask,
    float* __restrict__ out)
{
    __shared__ float Qs[64][68];
    __shared__ float Ks[64][68];   // K tile, then reused for P
    __shared__ float Vs[64][68];
    __shared__ int   am[64];

    const int bh = blockIdx.y;
    const int h  = bh % H_;
    const int b  = bh / H_;
    const int qt = gridDim.x - 1 - blockIdx.x;  // long diagonals dispatch first
    const int q0 = qt * 64;
    const int t  = threadIdx.x;
    const int tr = t >> 4;   // 0..15
    const int tc = t & 15;   // 0..15

    const float* __restrict__ Qg = Q + ((size_t)bh * M_ + q0) * DH_;
    const float* __restrict__ Kg = K + (size_t)bh * M_ * DH_;
    const float* __restrict__ Vg = V + (size_t)bh * M_ * DH_;

    // stage Q tile (scaled already)
    #pragma unroll
    for (int ch = 0; ch < 4; ++ch) {
        const int lin = ch * 256 + t;
        const int row = lin >> 4, c4 = (lin & 15) << 2;
        *(f32x4*)&Qs[row][c4] = *(const f32x4*)&Qg[row * DH_ + c4];
    }

    float o[4][4] = {{0.f}};
    float mrun[4], lrun[4];
    #pragma unroll
    for (int i = 0; i < 4; ++i) { mrun[i] = -3.0e38f; lrun[i] = 0.f; }

    for (int kt = 0; kt <= qt; ++kt) {
        __syncthreads();   // previous iteration done with Ks/Vs
        #pragma unroll
        for (int ch = 0; ch < 4; ++ch) {
            const int lin = ch * 256 + t;
            const int row = lin >> 4, c4 = (lin & 15) << 2;
            *(f32x4*)&Ks[row][c4] = *(const f32x4*)&Kg[((size_t)(kt*64 + row)) * DH_ + c4];
            *(f32x4*)&Vs[row][c4] = *(const f32x4*)&Vg[((size_t)(kt*64 + row)) * DH_ + c4];
        }
        if (t < 64) am[t] = amask[b * M_ + kt * 64 + t];
        __syncthreads();

        // ---- S = Qs · Ks^T (rows tr*4+i, cols tc+16j) ----
        float s[4][4] = {{0.f}};
        #pragma unroll
        for (int db = 0; db < 16; ++db) {
            f32x4 qv[4], kv[4];
            #pragma unroll
            for (int i = 0; i < 4; ++i) qv[i] = *(const f32x4*)&Qs[tr * 4 + i][db * 4];
            #pragma unroll
            for (int j = 0; j < 4; ++j) kv[j] = *(const f32x4*)&Ks[tc + 16 * j][db * 4];
            #pragma unroll
            for (int i = 0; i < 4; ++i)
                #pragma unroll
                for (int j = 0; j < 4; ++j)
                    s[i][j] += qv[i][0] * kv[j][0] + qv[i][1] * kv[j][1]
                             + qv[i][2] * kv[j][2] + qv[i][3] * kv[j][3];
        }

        // ---- mask + online softmax (row stats across the 16-lane tc group) ----
        float p[4][4];
        #pragma unroll
        for (int i = 0; i < 4; ++i) {
            const int gq = q0 + tr * 4 + i;
            float tm = -3.0e38f;
            #pragma unroll
            for (int j = 0; j < 4; ++j) {
                const int c = tc + 16 * j;
                const bool valid = ((kt * 64 + c) <= gq) && (am[c] > 0);
                s[i][j] = valid ? s[i][j] : NEGV;
                tm = fmaxf(tm, s[i][j]);
            }
            #pragma unroll
            for (int off = 1; off < 16; off <<= 1)
                tm = fmaxf(tm, __shfl_xor(tm, off));
            const float mnew  = fmaxf(mrun[i], tm);
            const float alpha = __expf(mrun[i] - mnew);
            mrun[i] = mnew;
            float ts = 0.f;
            #pragma unroll
            for (int j = 0; j < 4; ++j) {
                const float pj = __expf(s[i][j] - mnew);
                p[i][j] = pj;
                ts += pj;
            }
            #pragma unroll
            for (int off = 1; off < 16; off <<= 1)
                ts += __shfl_xor(ts, off);
            lrun[i] = lrun[i] * alpha + ts;
            #pragma unroll
            for (int j = 0; j < 4; ++j) o[i][j] *= alpha;
        }

        __syncthreads();   // everyone done reading Ks as K
        #pragma unroll
        for (int i = 0; i < 4; ++i)
            #pragma unroll
            for (int j = 0; j < 4; ++j)
                Ks[tr * 4 + i][tc + 16 * j] = p[i][j];   // Ks now holds P
        __syncthreads();

        // ---- O += P · V (rows tr*4+i, cols tc*4+j) ----
        #pragma unroll
        for (int kb = 0; kb < 16; ++kb) {
            f32x4 p4[4], v4[4];
            #pragma unroll
            for (int i = 0; i < 4; ++i)  p4[i]  = *(const f32x4*)&Ks[tr * 4 + i][kb * 4];
            #pragma unroll
            for (int kk = 0; kk < 4; ++kk) v4[kk] = *(const f32x4*)&Vs[kb * 4 + kk][tc * 4];
            #pragma unroll
            for (int i = 0; i < 4; ++i)
                #pragma unroll
                for (int j = 0; j < 4; ++j)
                    o[i][j] += p4[i][0] * v4[0][j] + p4[i][1] * v4[1][j]
                             + p4[i][2] * v4[2][j] + p4[i][3] * v4[3][j];
        }
    }

    // ---- epilogue: normalize, store (B,M,H,DH) ----
    #pragma unroll
    for (int i = 0; i < 4; ++i) {
        const float inv = (lrun[i] > 0.f) ? 1.f / lrun[i] : 0.f;
        const int gq = q0 + tr * 4 + i;
        f32x4 ov;
        ov[0] = o[i][0] * inv; ov[1] = o[i][1] * inv;
        ov[2] = o[i][2] * inv; ov[3] = o[i][3] * inv;
        *(f32x4*)&out[(((size_t)b * M_ + gq) * H_ + h) * DH_ + tc * 4] = ov;
    }
}

// ---------------------------------------------------------------------------
extern "C" void kernel_launch(void* const* d_in, const int* in_sizes, int n_in,
                              void* d_out, int out_size, void* d_ws, size_t ws_size,
                              hipStream_t stream)
{
    const float* Pq = (const float*)d_in[0];
    const float* Pk = (const float*)d_in[1];
    const float* Pv = (const float*)d_in[2];
    const float* Vq = (const float*)d_in[3];
    const float* Vk = (const float*)d_in[4];
    const float* Vv = (const float*)d_in[5];
    const float* bq = (const float*)d_in[6];
    const float* bk = (const float*)d_in[7];
    const float* bv = (const float*)d_in[8];
    const int*   am = (const int*)d_in[9];
    const int*   pid = (const int*)d_in[10];
    float* out = (float*)d_out;

    // workspace: 3 fp32 tensors of B*H*M*DH = 8388608 elems (33.55MB each,
    // 100.7MB total). Assumes ws_size >= 100663296.
    float* Qr = (float*)d_ws;
    float* Kr = Qr + (size_t)B_ * H_ * M_ * DH_;
    float* Vo = Kr + (size_t)B_ * H_ * M_ * DH_;

    const int rows = B_ * H_ * M_;
    qkv_rope_kernel<<<dim3(rows / 4), dim3(256), 0, stream>>>(
        Pq, Pk, Pv, Vq, Vk, Vv, bq, bk, bv, pid, Qr, Kr, Vo);

    flash_fp32_kernel<<<dim3(M_ / 64, B_ * H_), dim3(256), 0, stream>>>(
        Qr, Kr, Vo, am, out);
}

// Round 2
// 447.134 us; speedup vs baseline: 11.4289x; 11.4289x over previous
//
#include <hip/hip_runtime.h>
#include <math.h>

// FlashSVDRoPEAttention — round 2: bf16 MFMA attention + scalar-operand projection.
// B=4 H=16 M=2048 R=32 DH=64.
// Pipeline: rope_tab -> qkv_proj (bf16 Qb/Kb/Vb) -> vtrans (Vb->Vt) -> flash_mfma.

#define B_ 4
#define H_ 16
#define M_ 2048
#define R_ 32
#define DH_ 64
#define BH_ 64
#define NEGV -1.0e30f

typedef float  f32x4  __attribute__((ext_vector_type(4)));
typedef __bf16 bf16x8 __attribute__((ext_vector_type(8)));
typedef __bf16 bf16x4 __attribute__((ext_vector_type(4)));
typedef unsigned short ushort8 __attribute__((ext_vector_type(8)));

__device__ __forceinline__ unsigned short f2bf(float f) {
    unsigned u = __builtin_bit_cast(unsigned, f);
    u = (u + 0x7FFFu + ((u >> 16) & 1u)) >> 16;   // RNE
    return (unsigned short)u;
}

// ---------------------------------------------------------------------------
// cos/sin table: tab[b*M+m][0..15]=cos, [16..31]=sin  (freq idx fi = (d&31)>>1)
// ---------------------------------------------------------------------------
__global__ void rope_tab_kernel(const int* __restrict__ pid, float* __restrict__ tab)
{
    const int idx = blockIdx.x * 256 + threadIdx.x;   // B*M*16 threads exactly
    const int bm = idx >> 4, fi = idx & 15;
    const float invf = powf(10000.0f, -(float)fi * (1.0f / 32.0f));
    const float ang  = (float)pid[bm] * invf;
    float s, c;
    sincosf(ang, &s, &c);
    tab[(size_t)bm * 32 + fi]      = c;
    tab[(size_t)bm * 32 + 16 + fi] = s;
}

// ---------------------------------------------------------------------------
// Projection + RoPE. Wave job = (mat, bh, 64-row chunk). lane = d.
// V-matrix column resident in VGPRs; P-row coeffs via wave-uniform s_load.
// ---------------------------------------------------------------------------
__global__ __launch_bounds__(256) void qkv_proj_kernel(
    const float* __restrict__ Pq, const float* __restrict__ Pk,
    const float* __restrict__ Pv,
    const float* __restrict__ Vq, const float* __restrict__ Vk,
    const float* __restrict__ Vv,
    const float* __restrict__ bq, const float* __restrict__ bk,
    const float* __restrict__ bv,
    const float* __restrict__ tab,
    unsigned short* __restrict__ Qb, unsigned short* __restrict__ Kb,
    unsigned short* __restrict__ Vb)
{
    const int w    = threadIdx.x >> 6;
    const int lane = threadIdx.x & 63;
    const int gw   = blockIdx.x * 4 + w;      // 0..6143 (3 mats x 2048 chunks)
    const int mat  = gw >> 11;
    const int chunk = gw & 2047;
    const int bh = chunk >> 5;
    const int m0 = (chunk & 31) << 6;
    const int h = bh & (H_ - 1), b = bh >> 4;

    const float* P; const float* Vm; const float* bias; unsigned short* Out;
    if (mat == 0)      { P = Pq; Vm = Vq; bias = bq; Out = Qb; }
    else if (mat == 1) { P = Pk; Vm = Vk; bias = bk; Out = Kb; }
    else               { P = Pv; Vm = Vv; bias = bv; Out = Vb; }

    float vv[32];
    #pragma unroll
    for (int r = 0; r < 32; ++r) vv[r] = Vm[(h * 32 + r) * 64 + lane];
    const float bval = bias[h * 64 + lane];

    const int  fi   = (lane & 31) >> 1;
    const bool ishi = lane >= 32;
    const float scl = (mat == 0) ? 0.125f : 1.0f;    // fold 1/sqrt(64) into Q

    #pragma unroll 4
    for (int row = 0; row < 64; ++row) {
        const size_t ridx = (size_t)bh * M_ + m0 + row;
        const float* prow = P + ridx * 32;           // wave-uniform -> s_load
        float acc = bval;
        #pragma unroll
        for (int r = 0; r < 32; ++r) acc = fmaf(prow[r], vv[r], acc);
        float o;
        if (mat == 2) {
            o = acc;
        } else {
            const size_t bm = (size_t)b * M_ + m0 + row;
            const float c = tab[bm * 32 + fi];
            const float s = tab[bm * 32 + 16 + fi];
            const float partner = __shfl_xor(acc, 32);
            o = (acc * c + partner * (ishi ? s : -s)) * scl;
        }
        Out[ridx * 64 + lane] = f2bf(o);
    }
}

// ---------------------------------------------------------------------------
// V transpose: Vb [bh][m][64] -> Vt [bh][64][m]
// ---------------------------------------------------------------------------
__global__ __launch_bounds__(256) void vtrans_kernel(
    const unsigned short* __restrict__ Vb, unsigned short* __restrict__ Vt)
{
    __shared__ unsigned short tile[64][72];
    const int bh = blockIdx.y;
    const int m0 = blockIdx.x * 64;
    const int t  = threadIdx.x;
    {
        const int m = t >> 2, c0 = (t & 3) * 16;
        const unsigned short* g = Vb + ((size_t)bh * M_ + m0 + m) * 64 + c0;
        *(ushort8*)&tile[m][c0]     = *(const ushort8*)g;
        *(ushort8*)&tile[m][c0 + 8] = *(const ushort8*)(g + 8);
    }
    __syncthreads();
    {
        const int d = t >> 2, c0 = (t & 3) * 16;
        ushort8 a, c;
        #pragma unroll
        for (int j = 0; j < 8; ++j) a[j] = tile[c0 + j][d];
        #pragma unroll
        for (int j = 0; j < 8; ++j) c[j] = tile[c0 + 8 + j][d];
        unsigned short* o = Vt + ((size_t)(bh * 64 + d)) * M_ + m0 + c0;
        *(ushort8*)o       = a;
        *(ushort8*)(o + 8) = c;
    }
}

// ---------------------------------------------------------------------------
// Flash attention, bf16 MFMA 16x16x32, swapped operands.
// Block: 256 threads = 4 waves, 128 Q-rows (32/wave), 64-key tiles.
// S^T = mfma(A=K, B=Q): lane holds S^T[n=(g*4+reg)+16ni][q=c16+16qi].
// Softmax per q-col: in-lane reduce + shfl_xor(16,32).
// P^T stays in registers as PV's B-operand via phi(g,e)=4g+(e&3)+16(e>>2).
// O^T = mfma(A=V^T, B=P^T): lane holds O^T[d=(g*4+reg)+16di][q].
// ---------------------------------------------------------------------------
__global__ __launch_bounds__(256, 3) void flash_mfma_kernel(
    const unsigned short* __restrict__ Qus, const unsigned short* __restrict__ Kus,
    const unsigned short* __restrict__ Vtus, const int* __restrict__ amask,
    float* __restrict__ out)
{
    __shared__ unsigned short Ks[64 * 72];
    __shared__ unsigned short Vts[64 * 72];
    __shared__ int ams[64];

    const int bh = blockIdx.y;
    const int h  = bh & (H_ - 1), b = bh >> 4;
    const int qt = gridDim.x - 1 - blockIdx.x;    // heavy diagonals first
    const int q0 = qt * 128;
    const int t  = threadIdx.x;
    const int w  = t >> 6, lane = t & 63;
    const int c16 = lane & 15, g = lane >> 4;
    const int g4 = g * 4, g8 = g * 8;
    const int w32 = w * 32;

    // Q fragments resident (B-operand): qf[qi][kkd], lane c+16g holds Q[q][g*8+e]
    bf16x8 qf[2][2];
    #pragma unroll
    for (int qi = 0; qi < 2; ++qi)
        #pragma unroll
        for (int kkd = 0; kkd < 2; ++kkd)
            qf[qi][kkd] = *(const bf16x8*)(Qus +
                ((size_t)bh * M_ + q0 + w32 + qi * 16 + c16) * 64 + kkd * 32 + g8);

    const int qrow0 = q0 + w32 + c16;
    const int qrow1 = qrow0 + 16;

    f32x4 oT[4][2];
    const f32x4 zero4 = {0.f, 0.f, 0.f, 0.f};
    #pragma unroll
    for (int di = 0; di < 4; ++di) { oT[di][0] = zero4; oT[di][1] = zero4; }
    float mr[2] = {-3.0e38f, -3.0e38f};
    float lr[2] = {0.f, 0.f};

    const int nkt = 2 * qt + 2;
    for (int kt = 0; kt < nkt; ++kt) {
        const int n0 = kt * 64;
        __syncthreads();
        // ---- stage K tile and V^T tile ----
        {
            const int row = t >> 2, c0 = (t & 3) * 16;
            const unsigned short* gk = Kus + ((size_t)bh * M_ + n0 + row) * 64 + c0;
            *(ushort8*)&Ks[row * 72 + c0]     = *(const ushort8*)gk;
            *(ushort8*)&Ks[row * 72 + c0 + 8] = *(const ushort8*)(gk + 8);
            const unsigned short* gv = Vtus + ((size_t)(bh * 64 + row)) * M_ + n0 + c0;
            *(ushort8*)&Vts[row * 72 + c0]     = *(const ushort8*)gv;
            *(ushort8*)&Vts[row * 72 + c0 + 8] = *(const ushort8*)(gv + 8);
        }
        if (t < 64) ams[t] = amask[b * M_ + n0 + t];
        __syncthreads();

        // ---- S^T = K . Q^T ----
        f32x4 st[4][2];
        #pragma unroll
        for (int ni = 0; ni < 4; ++ni) { st[ni][0] = zero4; st[ni][1] = zero4; }
        #pragma unroll
        for (int kkd = 0; kkd < 2; ++kkd) {
            #pragma unroll
            for (int ni = 0; ni < 4; ++ni) {
                const bf16x8 kf = *(const bf16x8*)&Ks[(ni * 16 + c16) * 72 + kkd * 32 + g8];
                st[ni][0] = __builtin_amdgcn_mfma_f32_16x16x32_bf16(kf, qf[0][kkd], st[ni][0], 0, 0, 0);
                st[ni][1] = __builtin_amdgcn_mfma_f32_16x16x32_bf16(kf, qf[1][kkd], st[ni][1], 0, 0, 0);
            }
        }

        // ---- mask + online softmax (per q-column) ----
        bf16x8 pf[2][2];   // PV B-operand fragments [kk][qi]
        #pragma unroll
        for (int qi = 0; qi < 2; ++qi) {
            const int qrow = qi ? qrow1 : qrow0;
            float tm = -3.0e38f;
            #pragma unroll
            for (int ni = 0; ni < 4; ++ni)
                #pragma unroll
                for (int rg = 0; rg < 4; ++rg) {
                    const int n_loc = ni * 16 + g4 + rg;
                    const bool ok = ((n0 + n_loc) <= qrow) && (ams[n_loc] > 0);
                    const float sv = ok ? st[ni][qi][rg] : NEGV;
                    st[ni][qi][rg] = sv;
                    tm = fmaxf(tm, sv);
                }
            tm = fmaxf(tm, __shfl_xor(tm, 16));
            tm = fmaxf(tm, __shfl_xor(tm, 32));
            const float mnew  = fmaxf(mr[qi], tm);
            const float alpha = __expf(mr[qi] - mnew);
            float ts = 0.f;
            #pragma unroll
            for (int ni = 0; ni < 4; ++ni)
                #pragma unroll
                for (int rg = 0; rg < 4; ++rg) {
                    const float sv = st[ni][qi][rg];
                    const float pv = (sv > -1.0e29f) ? __expf(sv - mnew) : 0.f;
                    ts += pv;
                    pf[ni >> 1][qi][(ni & 1) * 4 + rg] = (__bf16)pv;
                }
            ts += __shfl_xor(ts, 16);
            ts += __shfl_xor(ts, 32);
            lr[qi] = lr[qi] * alpha + ts;
            mr[qi] = mnew;
            #pragma unroll
            for (int di = 0; di < 4; ++di)
                #pragma unroll
                for (int rg = 0; rg < 4; ++rg)
                    oT[di][qi][rg] *= alpha;
        }

        // ---- O^T += V^T . P^T ----
        #pragma unroll
        for (int di = 0; di < 4; ++di) {
            #pragma unroll
            for (int kk = 0; kk < 2; ++kk) {
                const int base = (di * 16 + c16) * 72 + kk * 32 + g4;
                const bf16x4 lo = *(const bf16x4*)&Vts[base];
                const bf16x4 hi = *(const bf16x4*)&Vts[base + 16];
                bf16x8 vf;
                vf[0] = lo[0]; vf[1] = lo[1]; vf[2] = lo[2]; vf[3] = lo[3];
                vf[4] = hi[0]; vf[5] = hi[1]; vf[6] = hi[2]; vf[7] = hi[3];
                oT[di][0] = __builtin_amdgcn_mfma_f32_16x16x32_bf16(vf, pf[kk][0], oT[di][0], 0, 0, 0);
                oT[di][1] = __builtin_amdgcn_mfma_f32_16x16x32_bf16(vf, pf[kk][1], oT[di][1], 0, 0, 0);
            }
        }
    }

    // ---- epilogue: normalize, store (B,M,H,DH) f32 ----
    float inv[2];
    inv[0] = (lr[0] > 0.f) ? 1.f / lr[0] : 0.f;
    inv[1] = (lr[1] > 0.f) ? 1.f / lr[1] : 0.f;
    #pragma unroll
    for (int di = 0; di < 4; ++di)
        #pragma unroll
        for (int qi = 0; qi < 2; ++qi) {
            const int q = q0 + w32 + qi * 16 + c16;
            #pragma unroll
            for (int rg = 0; rg < 4; ++rg) {
                const int d = di * 16 + g4 + rg;
                out[((size_t)(b * M_ + q) * H_ + h) * 64 + d] = oT[di][qi][rg] * inv[qi];
            }
        }
}

// ---------------------------------------------------------------------------
extern "C" void kernel_launch(void* const* d_in, const int* in_sizes, int n_in,
                              void* d_out, int out_size, void* d_ws, size_t ws_size,
                              hipStream_t stream)
{
    const float* Pq = (const float*)d_in[0];
    const float* Pk = (const float*)d_in[1];
    const float* Pv = (const float*)d_in[2];
    const float* Vq = (const float*)d_in[3];
    const float* Vk = (const float*)d_in[4];
    const float* Vv = (const float*)d_in[5];
    const float* bq = (const float*)d_in[6];
    const float* bk = (const float*)d_in[7];
    const float* bv = (const float*)d_in[8];
    const int*   am = (const int*)d_in[9];
    const int*   pid = (const int*)d_in[10];
    float* out = (float*)d_out;

    // workspace: tab 1MB | Qb,Kb,Vb,Vt bf16 16MB each = 68MB total
    float* tab = (float*)d_ws;
    unsigned short* Qb = (unsigned short*)((char*)d_ws + (1 << 20));
    unsigned short* Kb = Qb + (size_t)B_ * H_ * M_ * 64;
    unsigned short* Vb = Kb + (size_t)B_ * H_ * M_ * 64;
    unsigned short* Vt = Vb + (size_t)B_ * H_ * M_ * 64;

    rope_tab_kernel<<<dim3((B_ * M_ * 16) / 256), dim3(256), 0, stream>>>(pid, tab);

    qkv_proj_kernel<<<dim3(6144 / 4), dim3(256), 0, stream>>>(
        Pq, Pk, Pv, Vq, Vk, Vv, bq, bk, bv, tab, Qb, Kb, Vb);

    vtrans_kernel<<<dim3(M_ / 64, BH_), dim3(256), 0, stream>>>(Vb, Vt);

    flash_mfma_kernel<<<dim3(M_ / 128, BH_), dim3(256), 0, stream>>>(
        Qb, Kb, Vt, am, out);
}

// Round 3
// 277.313 us; speedup vs baseline: 18.4277x; 1.6124x over previous
//
#include <hip/hip_runtime.h>
#include <math.h>

// FlashSVDRoPEAttention — round 3.
// rope_tab + vt_prep -> qkv_proj_mfma (bf16 Qb/Kb/Vb) -> vtrans(phi) -> flash (paired tiles).

#define B_ 4
#define H_ 16
#define M_ 2048
#define R_ 32
#define DH_ 64
#define BH_ 64
#define NEGV -1.0e30f
#define LOG2E 1.4426950408889634f

typedef float  f32x4  __attribute__((ext_vector_type(4)));
typedef __bf16 bf16x8 __attribute__((ext_vector_type(8)));
typedef unsigned short ushort8 __attribute__((ext_vector_type(8)));

__device__ __forceinline__ unsigned short f2bf(float f) {
    unsigned u = __builtin_bit_cast(unsigned, f);
    u = (u + 0x7FFFu + ((u >> 16) & 1u)) >> 16;   // RNE
    return (unsigned short)u;
}
__device__ __forceinline__ __bf16 f2b(float f) {
    unsigned short u = f2bf(f);
    return __builtin_bit_cast(__bf16, u);
}

// ---------------------------------------------------------------------------
// cos/sin table: tab[b*M+m][0..15]=cos, [16..31]=sin (freq idx fi=(d&31)>>1)
// ---------------------------------------------------------------------------
__global__ void rope_tab_kernel(const int* __restrict__ pid, float* __restrict__ tab)
{
    const int idx = blockIdx.x * 256 + threadIdx.x;   // B*M*16 threads
    const int bm = idx >> 4, fi = idx & 15;
    const float invf = powf(10000.0f, -(float)fi * (1.0f / 32.0f));
    const float ang  = (float)pid[bm] * invf;
    float s, c;
    sincosf(ang, &s, &c);
    tab[(size_t)bm * 32 + fi]      = c;
    tab[(size_t)bm * 32 + 16 + fi] = s;
}

// ---------------------------------------------------------------------------
// VT precompute: VTb[mat][h][d][r] = bf16(V[h][r][d])  (3*16*64*32 elems)
// ---------------------------------------------------------------------------
__global__ void vt_prep_kernel(const float* __restrict__ Vq,
                               const float* __restrict__ Vk,
                               const float* __restrict__ Vv,
                               unsigned short* __restrict__ VTb)
{
    const int idx = blockIdx.x * 256 + threadIdx.x;   // 98304 threads
    const float* src = (idx < 32768) ? Vq : ((idx < 65536) ? Vk : Vv);
    const int rem = idx & 32767;
    const int h = rem >> 11, d = (rem >> 5) & 63, r = rem & 31;
    VTb[idx] = f2bf(src[(h * 32 + r) * 64 + d]);
}

// ---------------------------------------------------------------------------
// Projection via MFMA: C[m][d] = sum_r P[m][r] VT[d][r] + bias, then RoPE.
// K=32 = R in a single 16x16x32 MFMA. Layout anchors (verified by flash):
//   A-frag: lane c+16g holds A[row=c][k=g*8+e]
//   B-frag: lane c+16g holds B[row=c][k=g*8+e]
//   D:      lane c+16g holds D[Arow=4g+reg][Brow=c]
// RoPE partner d<->d^32 = di^2 tile, same lane, same reg -> no shuffles.
// Q gets 0.125*log2(e) folded in (exp2 softmax downstream).
// ---------------------------------------------------------------------------
__global__ __launch_bounds__(256) void qkv_proj_mfma_kernel(
    const float* __restrict__ Pq, const float* __restrict__ Pk,
    const float* __restrict__ Pv,
    const unsigned short* __restrict__ VTb,
    const float* __restrict__ bq, const float* __restrict__ bk,
    const float* __restrict__ bv,
    const float* __restrict__ tab,
    unsigned short* __restrict__ Qb, unsigned short* __restrict__ Kb,
    unsigned short* __restrict__ Vb)
{
    const int mat = blockIdx.z, bh = blockIdx.y, m0 = blockIdx.x * 128;
    const int h = bh & (H_ - 1), b = bh >> 4;
    const int t = threadIdx.x, w = t >> 6, lane = t & 63;
    const int c16 = lane & 15, g = lane >> 4, g8 = g << 3;

    const float* P    = (mat == 0) ? Pq : ((mat == 1) ? Pk : Pv);
    const float* bias = (mat == 0) ? bq : ((mat == 1) ? bk : bv);
    unsigned short* Out = (mat == 0) ? Qb : ((mat == 1) ? Kb : Vb);
    const float scl = (mat == 0) ? 0.125f * LOG2E : 1.0f;

    // B-frags: VT rows d = di*16 + c16
    bf16x8 vf[4];
    #pragma unroll
    for (int di = 0; di < 4; ++di)
        vf[di] = *(const bf16x8*)&VTb[((size_t)((mat * 16 + h) * 64 + di * 16 + c16)) * 32 + g8];

    // A-frags: P rows m = m0 + w*32 + mi*16 + c16
    bf16x8 af[2];
    #pragma unroll
    for (int mi = 0; mi < 2; ++mi) {
        const float* p = P + ((size_t)bh * M_ + m0 + w * 32 + mi * 16 + c16) * 32 + g8;
        const f32x4 lo = *(const f32x4*)p;
        const f32x4 hi = *(const f32x4*)(p + 4);
        #pragma unroll
        for (int e = 0; e < 4; ++e) { af[mi][e] = f2b(lo[e]); af[mi][4 + e] = f2b(hi[e]); }
    }

    f32x4 acc[2][4];
    const f32x4 z4 = {0.f, 0.f, 0.f, 0.f};
    #pragma unroll
    for (int mi = 0; mi < 2; ++mi)
        #pragma unroll
        for (int di = 0; di < 4; ++di)
            acc[mi][di] = z4;
    #pragma unroll
    for (int mi = 0; mi < 2; ++mi)
        #pragma unroll
        for (int di = 0; di < 4; ++di)
            acc[mi][di] = __builtin_amdgcn_mfma_f32_16x16x32_bf16(af[mi], vf[di], acc[mi][di], 0, 0, 0);

    float bsv[4];
    #pragma unroll
    for (int di = 0; di < 4; ++di) bsv[di] = bias[h * 64 + di * 16 + c16];

    #pragma unroll
    for (int mi = 0; mi < 2; ++mi)
        #pragma unroll
        for (int reg = 0; reg < 4; ++reg) {
            const int m = m0 + w * 32 + mi * 16 + (g << 2) + reg;
            const float x0 = acc[mi][0][reg] + bsv[0];
            const float x1 = acc[mi][1][reg] + bsv[1];
            const float x2 = acc[mi][2][reg] + bsv[2];
            const float x3 = acc[mi][3][reg] + bsv[3];
            const size_t o = ((size_t)bh * M_ + m) * 64;
            if (mat == 2) {
                Out[o + c16]      = f2bf(x0);
                Out[o + 16 + c16] = f2bf(x1);
                Out[o + 32 + c16] = f2bf(x2);
                Out[o + 48 + c16] = f2bf(x3);
            } else {
                const size_t bm = (size_t)b * M_ + m;
                const int fi = c16 >> 1;
                const float c0 = tab[bm * 32 + fi],     s0 = tab[bm * 32 + 16 + fi];
                const float c1 = tab[bm * 32 + 8 + fi], s1 = tab[bm * 32 + 24 + fi];
                Out[o + c16]      = f2bf((x0 * c0 - x2 * s0) * scl);
                Out[o + 16 + c16] = f2bf((x1 * c1 - x3 * s1) * scl);
                Out[o + 32 + c16] = f2bf((x0 * s0 + x2 * c0) * scl);
                Out[o + 48 + c16] = f2bf((x1 * s1 + x3 * c1) * scl);
            }
        }
}

// ---------------------------------------------------------------------------
// V transpose with phi-permutation within each 32-m group:
// Vt[bh][d][pos]: pos = g*8+e  <->  m_local = 4g + (e&3) + 16*(e>>2)
// so flash PV A-frag reads are contiguous b128 (same pattern as K reads).
// ---------------------------------------------------------------------------
__global__ __launch_bounds__(256) void vtrans_kernel(
    const unsigned short* __restrict__ Vb, unsigned short* __restrict__ Vt)
{
    __shared__ unsigned short tile[64][72];
    const int bh = blockIdx.y;
    const int m0 = blockIdx.x * 64;
    const int t  = threadIdx.x;
    {
        const int m = t >> 2, c0 = (t & 3) * 16;
        const unsigned short* gsrc = Vb + ((size_t)bh * M_ + m0 + m) * 64 + c0;
        *(ushort8*)&tile[m][c0]     = *(const ushort8*)gsrc;
        *(ushort8*)&tile[m][c0 + 8] = *(const ushort8*)(gsrc + 8);
    }
    __syncthreads();
    {
        const int d = t >> 2, sub = t & 3;
        const int mblk = sub >> 1, half = sub & 1;
        ushort8 a, c;
        #pragma unroll
        for (int i = 0; i < 8; ++i) {
            const int pos = half * 16 + i;
            const int gg = pos >> 3, e = pos & 7;
            a[i] = tile[mblk * 32 + 4 * gg + (e & 3) + 16 * (e >> 2)][d];
        }
        #pragma unroll
        for (int i = 0; i < 8; ++i) {
            const int pos = half * 16 + 8 + i;
            const int gg = pos >> 3, e = pos & 7;
            c[i] = tile[mblk * 32 + 4 * gg + (e & 3) + 16 * (e >> 2)][d];
        }
        unsigned short* o = Vt + ((size_t)(bh * 64 + d)) * M_ + m0 + mblk * 32 + half * 16;
        *(ushort8*)o       = a;
        *(ushort8*)(o + 8) = c;
    }
}

// ---------------------------------------------------------------------------
// Flash attention. Paired q-tiles (15-bx then bx): every block = 34 k-tiles.
// Reg-prefetch staging (T14), exp2 softmax, setprio around MFMA clusters.
// ---------------------------------------------------------------------------
__global__ __launch_bounds__(256, 2) void flash_mfma_kernel(
    const unsigned short* __restrict__ Qus, const unsigned short* __restrict__ Kus,
    const unsigned short* __restrict__ Vtus, const int* __restrict__ amask,
    float* __restrict__ out)
{
    __shared__ unsigned short Ks[64 * 72];
    __shared__ unsigned short Vts[64 * 72];
    __shared__ int ams[64];

    const int bh = blockIdx.y;
    const int h  = bh & (H_ - 1), b = bh >> 4;
    const int t  = threadIdx.x;
    const int w  = t >> 6, lane = t & 63;
    const int c16 = lane & 15, g = lane >> 4;
    const int g4 = g << 2, g8 = g << 3;
    const int w32 = w << 5;
    const int srow = t >> 2, sc0 = (t & 3) << 4;

    const unsigned short* Kg  = Kus  + (size_t)bh * M_ * 64;
    const unsigned short* Vtg = Vtus + (size_t)bh * 64 * M_;
    const f32x4 zero4 = {0.f, 0.f, 0.f, 0.f};

    for (int pick = 0; pick < 2; ++pick) {
        const int qt = pick ? blockIdx.x : (15 - blockIdx.x);   // heavy first
        const int q0 = qt << 7;
        const int nkt = 2 * qt + 2;

        bf16x8 qf[2][2];
        #pragma unroll
        for (int qi = 0; qi < 2; ++qi)
            #pragma unroll
            for (int kkd = 0; kkd < 2; ++kkd)
                qf[qi][kkd] = *(const bf16x8*)(Qus +
                    ((size_t)bh * M_ + q0 + w32 + qi * 16 + c16) * 64 + kkd * 32 + g8);
        const int qrow0 = q0 + w32 + c16;
        const int qrow1 = qrow0 + 16;

        f32x4 oT[4][2];
        #pragma unroll
        for (int di = 0; di < 4; ++di) { oT[di][0] = zero4; oT[di][1] = zero4; }
        float mr[2] = {-3.0e38f, -3.0e38f};
        float lr[2] = {0.f, 0.f};

        // prefetch kt=0
        ushort8 kreg0, kreg1, vreg0, vreg1;
        int amreg = 0;
        {
            const unsigned short* gk = Kg + (size_t)srow * 64 + sc0;
            kreg0 = *(const ushort8*)gk; kreg1 = *(const ushort8*)(gk + 8);
            const unsigned short* gv = Vtg + (size_t)srow * M_ + sc0;
            vreg0 = *(const ushort8*)gv; vreg1 = *(const ushort8*)(gv + 8);
            if (t < 64) amreg = amask[b * M_ + t];
        }

        for (int kt = 0; kt < nkt; ++kt) {
            const int n0 = kt << 6;
            __syncthreads();                       // prev tile fully consumed
            *(ushort8*)&Ks[srow * 72 + sc0]      = kreg0;
            *(ushort8*)&Ks[srow * 72 + sc0 + 8]  = kreg1;
            *(ushort8*)&Vts[srow * 72 + sc0]     = vreg0;
            *(ushort8*)&Vts[srow * 72 + sc0 + 8] = vreg1;
            if (t < 64) ams[t] = amreg;
            __syncthreads();

            if (kt + 1 < nkt) {                    // prefetch next tile
                const int n1 = n0 + 64;
                const unsigned short* gk = Kg + (size_t)(n1 + srow) * 64 + sc0;
                kreg0 = *(const ushort8*)gk; kreg1 = *(const ushort8*)(gk + 8);
                const unsigned short* gv = Vtg + (size_t)srow * M_ + n1 + sc0;
                vreg0 = *(const ushort8*)gv; vreg1 = *(const ushort8*)(gv + 8);
                if (t < 64) amreg = amask[b * M_ + n1 + t];
            }

            // ---- S^T = K . Q^T ----
            f32x4 st[4][2];
            #pragma unroll
            for (int ni = 0; ni < 4; ++ni) { st[ni][0] = zero4; st[ni][1] = zero4; }
            __builtin_amdgcn_s_setprio(1);
            #pragma unroll
            for (int kkd = 0; kkd < 2; ++kkd)
                #pragma unroll
                for (int ni = 0; ni < 4; ++ni) {
                    const bf16x8 kf = *(const bf16x8*)&Ks[(ni * 16 + c16) * 72 + kkd * 32 + g8];
                    st[ni][0] = __builtin_amdgcn_mfma_f32_16x16x32_bf16(kf, qf[0][kkd], st[ni][0], 0, 0, 0);
                    st[ni][1] = __builtin_amdgcn_mfma_f32_16x16x32_bf16(kf, qf[1][kkd], st[ni][1], 0, 0, 0);
                }
            __builtin_amdgcn_s_setprio(0);

            // ---- mask + online softmax (exp2 domain) ----
            bf16x8 pf[2][2];
            #pragma unroll
            for (int qi = 0; qi < 2; ++qi) {
                const int qrow = qi ? qrow1 : qrow0;
                float tm = -3.0e38f;
                #pragma unroll
                for (int ni = 0; ni < 4; ++ni)
                    #pragma unroll
                    for (int rg = 0; rg < 4; ++rg) {
                        const int n_loc = ni * 16 + g4 + rg;
                        const bool ok = ((n0 + n_loc) <= qrow) && (ams[n_loc] > 0);
                        const float sv = ok ? st[ni][qi][rg] : NEGV;
                        st[ni][qi][rg] = sv;
                        tm = fmaxf(tm, sv);
                    }
                tm = fmaxf(tm, __shfl_xor(tm, 16));
                tm = fmaxf(tm, __shfl_xor(tm, 32));
                const float mnew  = fmaxf(mr[qi], tm);
                const float alpha = exp2f(mr[qi] - mnew);
                float ts = 0.f;
                #pragma unroll
                for (int ni = 0; ni < 4; ++ni)
                    #pragma unroll
                    for (int rg = 0; rg < 4; ++rg) {
                        const float sv = st[ni][qi][rg];
                        const float pv = (sv > -1.0e29f) ? exp2f(sv - mnew) : 0.f;
                        ts += pv;
                        pf[ni >> 1][qi][(ni & 1) * 4 + rg] = f2b(pv);
                    }
                ts += __shfl_xor(ts, 16);
                ts += __shfl_xor(ts, 32);
                lr[qi] = lr[qi] * alpha + ts;
                mr[qi] = mnew;
                #pragma unroll
                for (int di = 0; di < 4; ++di)
                    #pragma unroll
                    for (int rg = 0; rg < 4; ++rg)
                        oT[di][qi][rg] *= alpha;
            }

            // ---- O^T += V^T . P^T (phi-permuted k, contiguous b128 reads) ----
            __builtin_amdgcn_s_setprio(1);
            #pragma unroll
            for (int di = 0; di < 4; ++di)
                #pragma unroll
                for (int kk = 0; kk < 2; ++kk) {
                    const bf16x8 vfr = *(const bf16x8*)&Vts[(di * 16 + c16) * 72 + kk * 32 + g8];
                    oT[di][0] = __builtin_amdgcn_mfma_f32_16x16x32_bf16(vfr, pf[kk][0], oT[di][0], 0, 0, 0);
                    oT[di][1] = __builtin_amdgcn_mfma_f32_16x16x32_bf16(vfr, pf[kk][1], oT[di][1], 0, 0, 0);
                }
            __builtin_amdgcn_s_setprio(0);
        }

        // ---- epilogue ----
        float inv[2];
        inv[0] = (lr[0] > 0.f) ? 1.f / lr[0] : 0.f;
        inv[1] = (lr[1] > 0.f) ? 1.f / lr[1] : 0.f;
        #pragma unroll
        for (int di = 0; di < 4; ++di)
            #pragma unroll
            for (int qi = 0; qi < 2; ++qi) {
                const int q = q0 + w32 + qi * 16 + c16;
                #pragma unroll
                for (int rg = 0; rg < 4; ++rg) {
                    const int d = di * 16 + g4 + rg;
                    out[((size_t)(b * M_ + q) * H_ + h) * 64 + d] = oT[di][qi][rg] * inv[qi];
                }
            }
    }
}

// ---------------------------------------------------------------------------
extern "C" void kernel_launch(void* const* d_in, const int* in_sizes, int n_in,
                              void* d_out, int out_size, void* d_ws, size_t ws_size,
                              hipStream_t stream)
{
    const float* Pq = (const float*)d_in[0];
    const float* Pk = (const float*)d_in[1];
    const float* Pv = (const float*)d_in[2];
    const float* Vq = (const float*)d_in[3];
    const float* Vk = (const float*)d_in[4];
    const float* Vv = (const float*)d_in[5];
    const float* bq = (const float*)d_in[6];
    const float* bk = (const float*)d_in[7];
    const float* bv = (const float*)d_in[8];
    const int*   am = (const int*)d_in[9];
    const int*   pid = (const int*)d_in[10];
    float* out = (float*)d_out;

    // workspace: tab 1MB | VTb 192KB (@1MB) | Qb,Kb,Vb,Vt bf16 16MB each (@2MB)
    float* tab = (float*)d_ws;
    unsigned short* VTb = (unsigned short*)((char*)d_ws + (1 << 20));
    unsigned short* Qb  = (unsigned short*)((char*)d_ws + (2 << 20));
    unsigned short* Kb = Qb + (size_t)B_ * H_ * M_ * 64;
    unsigned short* Vb = Kb + (size_t)B_ * H_ * M_ * 64;
    unsigned short* Vt = Vb + (size_t)B_ * H_ * M_ * 64;

    rope_tab_kernel<<<dim3((B_ * M_ * 16) / 256), dim3(256), 0, stream>>>(pid, tab);
    vt_prep_kernel<<<dim3(98304 / 256), dim3(256), 0, stream>>>(Vq, Vk, Vv, VTb);

    qkv_proj_mfma_kernel<<<dim3(16, 64, 3), dim3(256), 0, stream>>>(
        Pq, Pk, Pv, VTb, bq, bk, bv, tab, Qb, Kb, Vb);

    vtrans_kernel<<<dim3(M_ / 64, BH_), dim3(256), 0, stream>>>(Vb, Vt);

    flash_mfma_kernel<<<dim3(8, BH_), dim3(256), 0, stream>>>(
        Qb, Kb, Vt, am, out);
}

// Round 4
// 211.211 us; speedup vs baseline: 24.1949x; 1.3130x over previous
//
#include <hip/hip_runtime.h>
#include <math.h>

// FlashSVDRoPEAttention — round 4.
// prep (rope tab + VT bf16) -> qkv_proj_mfma (Qb, Kb, Vt-direct) -> flash.
// Flash: fast-path softmax (no mask ops interior), l-sum via ones-MFMA,
// defer-max rescale, native bf16 cvt, reg-prefetch staging.

#define B_ 4
#define H_ 16
#define M_ 2048
#define R_ 32
#define DH_ 64
#define BH_ 64
#define NEGV -1.0e30f
#define LOG2E 1.4426950408889634f

typedef float  f32x4  __attribute__((ext_vector_type(4)));
typedef __bf16 bf16x8 __attribute__((ext_vector_type(8)));
typedef unsigned short ushort8 __attribute__((ext_vector_type(8)));

__device__ __forceinline__ unsigned short bfbits(float f) {
    __bf16 h = (__bf16)f;
    return __builtin_bit_cast(unsigned short, h);
}

// ---------------------------------------------------------------------------
// prep: [0, 131072) rope cos/sin table; [131072, 229376) VT bf16 transpose.
// tab[bm][0..15]=cos, [16..31]=sin (fi=(d&31)>>1). VTb[mat][h][d][r].
// ---------------------------------------------------------------------------
__global__ void prep_kernel(const int* __restrict__ pid,
                            const float* __restrict__ Vq,
                            const float* __restrict__ Vk,
                            const float* __restrict__ Vv,
                            float* __restrict__ tab,
                            unsigned short* __restrict__ VTb)
{
    const int idx = blockIdx.x * 256 + threadIdx.x;
    if (idx < B_ * M_ * 16) {
        const int bm = idx >> 4, fi = idx & 15;
        const float invf = powf(10000.0f, -(float)fi * (1.0f / 32.0f));
        const float ang  = (float)pid[bm] * invf;
        float s, c;
        sincosf(ang, &s, &c);
        tab[(size_t)bm * 32 + fi]      = c;
        tab[(size_t)bm * 32 + 16 + fi] = s;
    } else {
        const int k = idx - B_ * M_ * 16;          // 0..98303
        const float* src = (k < 32768) ? Vq : ((k < 65536) ? Vk : Vv);
        const int rem = k & 32767;
        const int h = rem >> 11, d = (rem >> 5) & 63, r = rem & 31;
        VTb[k] = bfbits(src[(h * 32 + r) * 64 + d]);
    }
}

// ---------------------------------------------------------------------------
// Projection via MFMA (K=32=R, one 16x16x32 per tile).
//   A-frag: lane c+16g holds A[row=c][k=g*8+e]
//   D:      lane c+16g holds D[Arow=4g+reg][Brow=c]
// mat 0/1: RoPE epilogue (partner d^32 = di^2, same lane) -> Qb/Kb rows.
// mat 2:   writes Vt[bh][d][phi-pos] DIRECTLY: lane's 8 (mi,reg) values for
//          fixed d are exactly pos g*8 + (4mi+reg) -> one ushort8 store.
// ---------------------------------------------------------------------------
__global__ __launch_bounds__(256) void qkv_proj_mfma_kernel(
    const float* __restrict__ Pq, const float* __restrict__ Pk,
    const float* __restrict__ Pv,
    const unsigned short* __restrict__ VTb,
    const float* __restrict__ bq, const float* __restrict__ bk,
    const float* __restrict__ bv,
    const float* __restrict__ tab,
    unsigned short* __restrict__ Qb, unsigned short* __restrict__ Kb,
    unsigned short* __restrict__ Vt)
{
    const int mat = blockIdx.z, bh = blockIdx.y, m0 = blockIdx.x * 128;
    const int h = bh & (H_ - 1), b = bh >> 4;
    const int t = threadIdx.x, w = t >> 6, lane = t & 63;
    const int c16 = lane & 15, g = lane >> 4, g8 = g << 3;

    const float* P    = (mat == 0) ? Pq : ((mat == 1) ? Pk : Pv);
    const float* bias = (mat == 0) ? bq : ((mat == 1) ? bk : bv);
    const float scl = (mat == 0) ? 0.125f * LOG2E : 1.0f;

    bf16x8 vf[4];
    #pragma unroll
    for (int di = 0; di < 4; ++di)
        vf[di] = *(const bf16x8*)&VTb[((size_t)((mat * 16 + h) * 64 + di * 16 + c16)) * 32 + g8];

    bf16x8 af[2];
    #pragma unroll
    for (int mi = 0; mi < 2; ++mi) {
        const float* p = P + ((size_t)bh * M_ + m0 + w * 32 + mi * 16 + c16) * 32 + g8;
        const f32x4 lo = *(const f32x4*)p;
        const f32x4 hi = *(const f32x4*)(p + 4);
        #pragma unroll
        for (int e = 0; e < 4; ++e) { af[mi][e] = (__bf16)lo[e]; af[mi][4 + e] = (__bf16)hi[e]; }
    }

    f32x4 acc[2][4];
    const f32x4 z4 = {0.f, 0.f, 0.f, 0.f};
    #pragma unroll
    for (int mi = 0; mi < 2; ++mi)
        #pragma unroll
        for (int di = 0; di < 4; ++di)
            acc[mi][di] = __builtin_amdgcn_mfma_f32_16x16x32_bf16(af[mi], vf[di], z4, 0, 0, 0);

    float bsv[4];
    #pragma unroll
    for (int di = 0; di < 4; ++di) bsv[di] = bias[h * 64 + di * 16 + c16];

    if (mat == 2) {
        // Vt[bh][d][m0 + w*32 + 8g + (4mi+reg)]
        #pragma unroll
        for (int di = 0; di < 4; ++di) {
            ushort8 v8;
            #pragma unroll
            for (int mi = 0; mi < 2; ++mi)
                #pragma unroll
                for (int reg = 0; reg < 4; ++reg)
                    v8[(mi << 2) | reg] = bfbits(acc[mi][di][reg] + bsv[di]);
            const int d = di * 16 + c16;
            *(ushort8*)&Vt[((size_t)(bh * 64 + d)) * M_ + m0 + w * 32 + g8] = v8;
        }
    } else {
        unsigned short* Out = (mat == 0) ? Qb : Kb;
        #pragma unroll
        for (int mi = 0; mi < 2; ++mi)
            #pragma unroll
            for (int reg = 0; reg < 4; ++reg) {
                const int m = m0 + w * 32 + mi * 16 + (g << 2) + reg;
                const float x0 = acc[mi][0][reg] + bsv[0];
                const float x1 = acc[mi][1][reg] + bsv[1];
                const float x2 = acc[mi][2][reg] + bsv[2];
                const float x3 = acc[mi][3][reg] + bsv[3];
                const size_t o = ((size_t)bh * M_ + m) * 64;
                const size_t bm = (size_t)b * M_ + m;
                const int fi = c16 >> 1;
                const float c0 = tab[bm * 32 + fi],     s0 = tab[bm * 32 + 16 + fi];
                const float c1 = tab[bm * 32 + 8 + fi], s1 = tab[bm * 32 + 24 + fi];
                Out[o + c16]      = bfbits((x0 * c0 - x2 * s0) * scl);
                Out[o + 16 + c16] = bfbits((x1 * c1 - x3 * s1) * scl);
                Out[o + 32 + c16] = bfbits((x0 * s0 + x2 * c0) * scl);
                Out[o + 48 + c16] = bfbits((x1 * s1 + x3 * c1) * scl);
            }
    }
}

// ---------------------------------------------------------------------------
// Flash attention. Paired q-tiles (15-bx, bx) = 34 k-tiles/block uniform.
// Fast-path softmax: interior tiles have zero mask ops; l via ones-MFMA;
// defer-max rescale (THR=7, log2 domain); exp2 softmax.
// ---------------------------------------------------------------------------
__global__ __launch_bounds__(256, 3) void flash_mfma_kernel(
    const unsigned short* __restrict__ Qus, const unsigned short* __restrict__ Kus,
    const unsigned short* __restrict__ Vtus, const int* __restrict__ amask,
    float* __restrict__ out)
{
    __shared__ unsigned short Ks[64 * 72];
    __shared__ unsigned short Vts[64 * 72];
    __shared__ int ams[64];

    const int bh = blockIdx.y;
    const int h  = bh & (H_ - 1), b = bh >> 4;
    const int t  = threadIdx.x;
    const int w  = t >> 6, lane = t & 63;
    const int c16 = lane & 15, g = lane >> 4;
    const int g4 = g << 2, g8 = g << 3;
    const int w32 = w << 5;
    const int srow = t >> 2, sc0 = (t & 3) << 4;

    const unsigned short* Kg  = Kus  + (size_t)bh * M_ * 64;
    const unsigned short* Vtg = Vtus + (size_t)bh * 64 * M_;
    const f32x4 zero4 = {0.f, 0.f, 0.f, 0.f};

    bf16x8 onesf;
    #pragma unroll
    for (int e = 0; e < 8; ++e) onesf[e] = (__bf16)1.0f;

    for (int pick = 0; pick < 2; ++pick) {
        const int qt = pick ? blockIdx.x : (15 - blockIdx.x);
        const int q0 = qt << 7;
        const int nkt = 2 * qt + 2;

        bf16x8 qf[2][2];
        #pragma unroll
        for (int qi = 0; qi < 2; ++qi)
            #pragma unroll
            for (int kkd = 0; kkd < 2; ++kkd)
                qf[qi][kkd] = *(const bf16x8*)(Qus +
                    ((size_t)bh * M_ + q0 + w32 + qi * 16 + c16) * 64 + kkd * 32 + g8);
        const int qrow0 = q0 + w32 + c16;
        const int qrow1 = qrow0 + 16;

        f32x4 oT[4][2];
        #pragma unroll
        for (int di = 0; di < 4; ++di) { oT[di][0] = zero4; oT[di][1] = zero4; }
        f32x4 lacc[2] = {zero4, zero4};
        float mr[2] = {-3.0e38f, -3.0e38f};

        // prefetch kt=0
        ushort8 kreg0, kreg1, vreg0, vreg1;
        int amreg = 0;
        {
            const unsigned short* gk = Kg + (size_t)srow * 64 + sc0;
            kreg0 = *(const ushort8*)gk; kreg1 = *(const ushort8*)(gk + 8);
            const unsigned short* gv = Vtg + (size_t)srow * M_ + sc0;
            vreg0 = *(const ushort8*)gv; vreg1 = *(const ushort8*)(gv + 8);
            if (t < 64) amreg = amask[b * M_ + t];
        }

        for (int kt = 0; kt < nkt; ++kt) {
            const int n0 = kt << 6;
            __syncthreads();
            *(ushort8*)&Ks[srow * 72 + sc0]      = kreg0;
            *(ushort8*)&Ks[srow * 72 + sc0 + 8]  = kreg1;
            *(ushort8*)&Vts[srow * 72 + sc0]     = vreg0;
            *(ushort8*)&Vts[srow * 72 + sc0 + 8] = vreg1;
            if (t < 64) ams[t] = amreg;
            __syncthreads();

            if (kt + 1 < nkt) {
                const int n1 = n0 + 64;
                const unsigned short* gk = Kg + (size_t)(n1 + srow) * 64 + sc0;
                kreg0 = *(const ushort8*)gk; kreg1 = *(const ushort8*)(gk + 8);
                const unsigned short* gv = Vtg + (size_t)srow * M_ + n1 + sc0;
                vreg0 = *(const ushort8*)gv; vreg1 = *(const ushort8*)(gv + 8);
                if (t < 64) amreg = amask[b * M_ + n1 + t];
            }

            // ---- S^T = K . Q^T ----
            f32x4 st[4][2];
            #pragma unroll
            for (int ni = 0; ni < 4; ++ni) { st[ni][0] = zero4; st[ni][1] = zero4; }
            __builtin_amdgcn_s_setprio(1);
            #pragma unroll
            for (int kkd = 0; kkd < 2; ++kkd)
                #pragma unroll
                for (int ni = 0; ni < 4; ++ni) {
                    const bf16x8 kf = *(const bf16x8*)&Ks[(ni * 16 + c16) * 72 + kkd * 32 + g8];
                    st[ni][0] = __builtin_amdgcn_mfma_f32_16x16x32_bf16(kf, qf[0][kkd], st[ni][0], 0, 0, 0);
                    st[ni][1] = __builtin_amdgcn_mfma_f32_16x16x32_bf16(kf, qf[1][kkd], st[ni][1], 0, 0, 0);
                }
            __builtin_amdgcn_s_setprio(0);

            // ---- softmax ----
            const bool allv  = __all(ams[lane] > 0);          // wave-uniform
            const bool needc = (n0 + 63) > (q0 + w32);        // wave-uniform
            bf16x8 pf[2][2];
            #pragma unroll
            for (int qi = 0; qi < 2; ++qi) {
                const int qrow = qi ? qrow1 : qrow0;
                float tm = -3.0e38f;
                if (allv) {
                    if (needc) {
                        #pragma unroll
                        for (int ni = 0; ni < 4; ++ni)
                            #pragma unroll
                            for (int rg = 0; rg < 4; ++rg) {
                                const int n_loc = ni * 16 + g4 + rg;
                                const float sv = ((n0 + n_loc) <= qrow) ? st[ni][qi][rg] : NEGV;
                                st[ni][qi][rg] = sv;
                                tm = fmaxf(tm, sv);
                            }
                    } else {
                        #pragma unroll
                        for (int ni = 0; ni < 4; ++ni)
                            #pragma unroll
                            for (int rg = 0; rg < 4; ++rg)
                                tm = fmaxf(tm, st[ni][qi][rg]);
                    }
                } else {
                    #pragma unroll
                    for (int ni = 0; ni < 4; ++ni)
                        #pragma unroll
                        for (int rg = 0; rg < 4; ++rg) {
                            const int n_loc = ni * 16 + g4 + rg;
                            const bool ok = ((n0 + n_loc) <= qrow) && (ams[n_loc] > 0);
                            const float sv = ok ? st[ni][qi][rg] : NEGV;
                            st[ni][qi][rg] = sv;
                            tm = fmaxf(tm, sv);
                        }
                }
                tm = fmaxf(tm, __shfl_xor(tm, 16));
                tm = fmaxf(tm, __shfl_xor(tm, 32));
                const bool skip = __all(tm <= mr[qi] + 7.0f);
                if (!skip) {
                    const float mnew  = fmaxf(mr[qi], tm);
                    const float alpha = exp2f(mr[qi] - mnew);
                    mr[qi] = mnew;
                    #pragma unroll
                    for (int di = 0; di < 4; ++di)
                        #pragma unroll
                        for (int rg = 0; rg < 4; ++rg)
                            oT[di][qi][rg] *= alpha;
                    lacc[qi][0] *= alpha;
                }
                const float mcur = mr[qi];
                if (allv) {
                    #pragma unroll
                    for (int ni = 0; ni < 4; ++ni)
                        #pragma unroll
                        for (int rg = 0; rg < 4; ++rg)
                            pf[ni >> 1][qi][((ni & 1) << 2) | rg] =
                                (__bf16)exp2f(st[ni][qi][rg] - mcur);
                } else {
                    #pragma unroll
                    for (int ni = 0; ni < 4; ++ni)
                        #pragma unroll
                        for (int rg = 0; rg < 4; ++rg) {
                            const float sv = st[ni][qi][rg];
                            const float pv = (sv > -1.0e29f) ? exp2f(sv - mcur) : 0.f;
                            pf[ni >> 1][qi][((ni & 1) << 2) | rg] = (__bf16)pv;
                        }
                }
            }

            // ---- l-sum + O^T += V^T . P^T ----
            __builtin_amdgcn_s_setprio(1);
            lacc[0] = __builtin_amdgcn_mfma_f32_16x16x32_bf16(onesf, pf[0][0], lacc[0], 0, 0, 0);
            lacc[0] = __builtin_amdgcn_mfma_f32_16x16x32_bf16(onesf, pf[1][0], lacc[0], 0, 0, 0);
            lacc[1] = __builtin_amdgcn_mfma_f32_16x16x32_bf16(onesf, pf[0][1], lacc[1], 0, 0, 0);
            lacc[1] = __builtin_amdgcn_mfma_f32_16x16x32_bf16(onesf, pf[1][1], lacc[1], 0, 0, 0);
            #pragma unroll
            for (int di = 0; di < 4; ++di)
                #pragma unroll
                for (int kk = 0; kk < 2; ++kk) {
                    const bf16x8 vfr = *(const bf16x8*)&Vts[(di * 16 + c16) * 72 + kk * 32 + g8];
                    oT[di][0] = __builtin_amdgcn_mfma_f32_16x16x32_bf16(vfr, pf[kk][0], oT[di][0], 0, 0, 0);
                    oT[di][1] = __builtin_amdgcn_mfma_f32_16x16x32_bf16(vfr, pf[kk][1], oT[di][1], 0, 0, 0);
                }
            __builtin_amdgcn_s_setprio(0);
        }

        // ---- epilogue: f32x4 stores ----
        float inv[2];
        inv[0] = (lacc[0][0] > 0.f) ? 1.f / lacc[0][0] : 0.f;
        inv[1] = (lacc[1][0] > 0.f) ? 1.f / lacc[1][0] : 0.f;
        #pragma unroll
        for (int di = 0; di < 4; ++di)
            #pragma unroll
            for (int qi = 0; qi < 2; ++qi) {
                const int q = q0 + w32 + qi * 16 + c16;
                f32x4 ov;
                #pragma unroll
                for (int rg = 0; rg < 4; ++rg) ov[rg] = oT[di][qi][rg] * inv[qi];
                *(f32x4*)&out[((size_t)(b * M_ + q) * H_ + h) * 64 + di * 16 + g4] = ov;
            }
    }
}

// ---------------------------------------------------------------------------
extern "C" void kernel_launch(void* const* d_in, const int* in_sizes, int n_in,
                              void* d_out, int out_size, void* d_ws, size_t ws_size,
                              hipStream_t stream)
{
    const float* Pq = (const float*)d_in[0];
    const float* Pk = (const float*)d_in[1];
    const float* Pv = (const float*)d_in[2];
    const float* Vq = (const float*)d_in[3];
    const float* Vk = (const float*)d_in[4];
    const float* Vv = (const float*)d_in[5];
    const float* bq = (const float*)d_in[6];
    const float* bk = (const float*)d_in[7];
    const float* bv = (const float*)d_in[8];
    const int*   am = (const int*)d_in[9];
    const int*   pid = (const int*)d_in[10];
    float* out = (float*)d_out;

    // workspace: tab 1MB | VTb 192KB (@1MB) | Qb,Kb,Vt bf16 16MB each (@2MB)
    float* tab = (float*)d_ws;
    unsigned short* VTb = (unsigned short*)((char*)d_ws + (1 << 20));
    unsigned short* Qb  = (unsigned short*)((char*)d_ws + (2 << 20));
    unsigned short* Kb = Qb + (size_t)B_ * H_ * M_ * 64;
    unsigned short* Vt = Kb + (size_t)B_ * H_ * M_ * 64;

    prep_kernel<<<dim3((B_ * M_ * 16 + 98304) / 256), dim3(256), 0, stream>>>(
        pid, Vq, Vk, Vv, tab, VTb);

    qkv_proj_mfma_kernel<<<dim3(16, 64, 3), dim3(256), 0, stream>>>(
        Pq, Pk, Pv, VTb, bq, bk, bv, tab, Qb, Kb, Vt);

    flash_mfma_kernel<<<dim3(8, BH_), dim3(256), 0, stream>>>(
        Qb, Kb, Vt, am, out);
}

// Round 6
// 200.226 us; speedup vs baseline: 25.5224x; 1.0549x over previous
//
#include <hip/hip_runtime.h>
#include <math.h>

// FlashSVDRoPEAttention — round 6 (round-5 retry; ushort4 name collision fixed).
// prep (rope tab + VT bf16) -> qkv_proj_mfma (LDS-staged P) -> flash.
// Flash: 64-row q-tiles (grid 1024 = 4 blocks/CU), XCD-aware bh grouping,
// paired q-tiles, fast-path softmax, ones-MFMA l-sum, defer-max, exp2.

#define B_ 4
#define H_ 16
#define M_ 2048
#define R_ 32
#define DH_ 64
#define BH_ 64
#define NEGV -1.0e30f
#define LOG2E 1.4426950408889634f

typedef float  f32x4  __attribute__((ext_vector_type(4)));
typedef __bf16 bf16x8 __attribute__((ext_vector_type(8)));
typedef unsigned short u16x4 __attribute__((ext_vector_type(4)));
typedef unsigned short u16x8 __attribute__((ext_vector_type(8)));

__device__ __forceinline__ unsigned short bfbits(float f) {
    __bf16 h = (__bf16)f;
    return __builtin_bit_cast(unsigned short, h);
}

// ---------------------------------------------------------------------------
// prep: [0, 131072) rope cos/sin table; [131072, 229376) VT bf16 transpose.
// tab[bm][0..15]=cos, [16..31]=sin (fi=(d&31)>>1). VTb[mat][h][d][r].
// ---------------------------------------------------------------------------
__global__ void prep_kernel(const int* __restrict__ pid,
                            const float* __restrict__ Vq,
                            const float* __restrict__ Vk,
                            const float* __restrict__ Vv,
                            float* __restrict__ tab,
                            unsigned short* __restrict__ VTb)
{
    const int idx = blockIdx.x * 256 + threadIdx.x;
    if (idx < B_ * M_ * 16) {
        const int bm = idx >> 4, fi = idx & 15;
        const float invf = powf(10000.0f, -(float)fi * (1.0f / 32.0f));
        const float ang  = (float)pid[bm] * invf;
        float s, c;
        sincosf(ang, &s, &c);
        tab[(size_t)bm * 32 + fi]      = c;
        tab[(size_t)bm * 32 + 16 + fi] = s;
    } else {
        const int k = idx - B_ * M_ * 16;          // 0..98303
        const float* src = (k < 32768) ? Vq : ((k < 65536) ? Vk : Vv);
        const int rem = k & 32767;
        const int h = rem >> 11, d = (rem >> 5) & 63, r = rem & 31;
        VTb[k] = bfbits(src[(h * 32 + r) * 64 + d]);
    }
}

// ---------------------------------------------------------------------------
// Projection via MFMA (K=32=R). P tile staged coalesced through LDS as bf16.
//   A-frag: lane c+16g holds A[row=c][k=g*8+e]
//   D:      lane c+16g holds D[Arow=4g+reg][Brow=c]
// mat 0/1: RoPE epilogue (partner d^32 = di^2, same lane) -> Qb/Kb rows.
// mat 2:   writes Vt[bh][d][phi-pos] directly (pos = 8g + 4mi + reg).
// ---------------------------------------------------------------------------
__global__ __launch_bounds__(256) void qkv_proj_mfma_kernel(
    const float* __restrict__ Pq, const float* __restrict__ Pk,
    const float* __restrict__ Pv,
    const unsigned short* __restrict__ VTb,
    const float* __restrict__ bq, const float* __restrict__ bk,
    const float* __restrict__ bv,
    const float* __restrict__ tab,
    unsigned short* __restrict__ Qb, unsigned short* __restrict__ Kb,
    unsigned short* __restrict__ Vt)
{
    __shared__ unsigned short Ps[128 * 40];   // pad 40: b128-aligned frag reads

    const int mat = blockIdx.z, bh = blockIdx.y, m0 = blockIdx.x * 128;
    const int h = bh & (H_ - 1), b = bh >> 4;
    const int t = threadIdx.x, w = t >> 6, lane = t & 63;
    const int c16 = lane & 15, g = lane >> 4, g8 = g << 3;

    const float* P    = (mat == 0) ? Pq : ((mat == 1) ? Pk : Pv);
    const float* bias = (mat == 0) ? bq : ((mat == 1) ? bk : bv);
    const float scl = (mat == 0) ? 0.125f * LOG2E : 1.0f;

    // stage P[128][32] fp32 -> bf16 LDS, fully coalesced
    const float* Pg = P + ((size_t)bh * M_ + m0) * 32;
    #pragma unroll
    for (int pass = 0; pass < 4; ++pass) {
        const int lin = pass * 256 + t;           // float4 unit
        const int row = lin >> 3, c4 = (lin & 7) << 2;
        const f32x4 v = *(const f32x4*)&Pg[row * 32 + c4];
        u16x4 b4;
        #pragma unroll
        for (int e = 0; e < 4; ++e) b4[e] = bfbits(v[e]);
        *(u16x4*)&Ps[row * 40 + c4] = b4;
    }

    bf16x8 vf[4];
    #pragma unroll
    for (int di = 0; di < 4; ++di)
        vf[di] = *(const bf16x8*)&VTb[((size_t)((mat * 16 + h) * 64 + di * 16 + c16)) * 32 + g8];

    __syncthreads();

    bf16x8 af[2];
    #pragma unroll
    for (int mi = 0; mi < 2; ++mi)
        af[mi] = *(const bf16x8*)&Ps[(w * 32 + mi * 16 + c16) * 40 + g8];

    f32x4 acc[2][4];
    const f32x4 z4 = {0.f, 0.f, 0.f, 0.f};
    #pragma unroll
    for (int mi = 0; mi < 2; ++mi)
        #pragma unroll
        for (int di = 0; di < 4; ++di)
            acc[mi][di] = __builtin_amdgcn_mfma_f32_16x16x32_bf16(af[mi], vf[di], z4, 0, 0, 0);

    float bsv[4];
    #pragma unroll
    for (int di = 0; di < 4; ++di) bsv[di] = bias[h * 64 + di * 16 + c16];

    if (mat == 2) {
        #pragma unroll
        for (int di = 0; di < 4; ++di) {
            u16x8 v8;
            #pragma unroll
            for (int mi = 0; mi < 2; ++mi)
                #pragma unroll
                for (int reg = 0; reg < 4; ++reg)
                    v8[(mi << 2) | reg] = bfbits(acc[mi][di][reg] + bsv[di]);
            const int d = di * 16 + c16;
            *(u16x8*)&Vt[((size_t)(bh * 64 + d)) * M_ + m0 + w * 32 + g8] = v8;
        }
    } else {
        unsigned short* Out = (mat == 0) ? Qb : Kb;
        #pragma unroll
        for (int mi = 0; mi < 2; ++mi)
            #pragma unroll
            for (int reg = 0; reg < 4; ++reg) {
                const int m = m0 + w * 32 + mi * 16 + (g << 2) + reg;
                const float x0 = acc[mi][0][reg] + bsv[0];
                const float x1 = acc[mi][1][reg] + bsv[1];
                const float x2 = acc[mi][2][reg] + bsv[2];
                const float x3 = acc[mi][3][reg] + bsv[3];
                const size_t o = ((size_t)bh * M_ + m) * 64;
                const size_t bm = (size_t)b * M_ + m;
                const int fi = c16 >> 1;
                const float c0 = tab[bm * 32 + fi],     s0 = tab[bm * 32 + 16 + fi];
                const float c1 = tab[bm * 32 + 8 + fi], s1 = tab[bm * 32 + 24 + fi];
                Out[o + c16]      = bfbits((x0 * c0 - x2 * s0) * scl);
                Out[o + 16 + c16] = bfbits((x1 * c1 - x3 * s1) * scl);
                Out[o + 32 + c16] = bfbits((x0 * s0 + x2 * c0) * scl);
                Out[o + 48 + c16] = bfbits((x1 * s1 + x3 * c1) * scl);
            }
    }
}

// ---------------------------------------------------------------------------
// Flash attention. 1D grid 1024: xcd=bid&7 owns bh in [xcd*8, xcd*8+8)
// (K/V working set 4MB = one XCD L2). Block = 64 q-rows, 4 waves x 16 rows.
// Paired q-tiles {31-px, px} -> 33 k-tiles/block uniform.
// ---------------------------------------------------------------------------
__global__ __launch_bounds__(256, 4) void flash_mfma_kernel(
    const unsigned short* __restrict__ Qus, const unsigned short* __restrict__ Kus,
    const unsigned short* __restrict__ Vtus, const int* __restrict__ amask,
    float* __restrict__ out)
{
    __shared__ unsigned short Ks[64 * 72];
    __shared__ unsigned short Vts[64 * 72];
    __shared__ int ams[64];

    const int bid = blockIdx.x;
    const int xcd = bid & 7, loc = bid >> 3;
    const int bh  = xcd * 8 + (loc & 7);
    const int px  = loc >> 3;                 // 0..15
    const int h = bh & (H_ - 1), b = bh >> 4;
    const int t = threadIdx.x;
    const int w = t >> 6, lane = t & 63;
    const int c16 = lane & 15, g = lane >> 4;
    const int g4 = g << 2, g8 = g << 3;
    const int w16 = w << 4;
    const int srow = t >> 2, sc0 = (t & 3) << 4;

    const unsigned short* Kg  = Kus  + (size_t)bh * M_ * 64;
    const unsigned short* Vtg = Vtus + (size_t)bh * 64 * M_;
    const f32x4 zero4 = {0.f, 0.f, 0.f, 0.f};

    bf16x8 onesf;
    #pragma unroll
    for (int e = 0; e < 8; ++e) onesf[e] = (__bf16)1.0f;

    for (int pick = 0; pick < 2; ++pick) {
        const int qt = pick ? px : (31 - px);
        const int q0 = qt << 6;
        const int nkt = qt + 1;

        bf16x8 qf[2];
        #pragma unroll
        for (int kkd = 0; kkd < 2; ++kkd)
            qf[kkd] = *(const bf16x8*)(Qus +
                ((size_t)bh * M_ + q0 + w16 + c16) * 64 + kkd * 32 + g8);
        const int qrow = q0 + w16 + c16;

        f32x4 oT[4];
        #pragma unroll
        for (int di = 0; di < 4; ++di) oT[di] = zero4;
        f32x4 lacc = zero4;
        float mr = -3.0e38f;

        // prefetch kt=0
        u16x8 kreg0, kreg1, vreg0, vreg1;
        int amreg = 0;
        {
            const unsigned short* gk = Kg + (size_t)srow * 64 + sc0;
            kreg0 = *(const u16x8*)gk; kreg1 = *(const u16x8*)(gk + 8);
            const unsigned short* gv = Vtg + (size_t)srow * M_ + sc0;
            vreg0 = *(const u16x8*)gv; vreg1 = *(const u16x8*)(gv + 8);
            if (t < 64) amreg = amask[b * M_ + t];
        }

        for (int kt = 0; kt < nkt; ++kt) {
            const int n0 = kt << 6;
            __syncthreads();
            *(u16x8*)&Ks[srow * 72 + sc0]      = kreg0;
            *(u16x8*)&Ks[srow * 72 + sc0 + 8]  = kreg1;
            *(u16x8*)&Vts[srow * 72 + sc0]     = vreg0;
            *(u16x8*)&Vts[srow * 72 + sc0 + 8] = vreg1;
            if (t < 64) ams[t] = amreg;
            __syncthreads();

            if (kt + 1 < nkt) {
                const int n1 = n0 + 64;
                const unsigned short* gk = Kg + (size_t)(n1 + srow) * 64 + sc0;
                kreg0 = *(const u16x8*)gk; kreg1 = *(const u16x8*)(gk + 8);
                const unsigned short* gv = Vtg + (size_t)srow * M_ + n1 + sc0;
                vreg0 = *(const u16x8*)gv; vreg1 = *(const u16x8*)(gv + 8);
                if (t < 64) amreg = amask[b * M_ + n1 + t];
            }

            // ---- S^T = K . Q^T ----
            f32x4 st[4];
            #pragma unroll
            for (int ni = 0; ni < 4; ++ni) st[ni] = zero4;
            __builtin_amdgcn_s_setprio(1);
            #pragma unroll
            for (int kkd = 0; kkd < 2; ++kkd)
                #pragma unroll
                for (int ni = 0; ni < 4; ++ni) {
                    const bf16x8 kf = *(const bf16x8*)&Ks[(ni * 16 + c16) * 72 + kkd * 32 + g8];
                    st[ni] = __builtin_amdgcn_mfma_f32_16x16x32_bf16(kf, qf[kkd], st[ni], 0, 0, 0);
                }
            __builtin_amdgcn_s_setprio(0);

            // ---- softmax ----
            const bool allv  = __all(ams[lane] > 0);          // wave-uniform
            const bool needc = (n0 + 63) > (q0 + w16);        // wave-uniform
            bf16x8 pf[2];
            {
                float tm = -3.0e38f;
                if (allv) {
                    if (needc) {
                        #pragma unroll
                        for (int ni = 0; ni < 4; ++ni)
                            #pragma unroll
                            for (int rg = 0; rg < 4; ++rg) {
                                const int n_loc = ni * 16 + g4 + rg;
                                const float sv = ((n0 + n_loc) <= qrow) ? st[ni][rg] : NEGV;
                                st[ni][rg] = sv;
                                tm = fmaxf(tm, sv);
                            }
                    } else {
                        #pragma unroll
                        for (int ni = 0; ni < 4; ++ni)
                            #pragma unroll
                            for (int rg = 0; rg < 4; ++rg)
                                tm = fmaxf(tm, st[ni][rg]);
                    }
                } else {
                    #pragma unroll
                    for (int ni = 0; ni < 4; ++ni)
                        #pragma unroll
                        for (int rg = 0; rg < 4; ++rg) {
                            const int n_loc = ni * 16 + g4 + rg;
                            const bool ok = ((n0 + n_loc) <= qrow) && (ams[n_loc] > 0);
                            const float sv = ok ? st[ni][rg] : NEGV;
                            st[ni][rg] = sv;
                            tm = fmaxf(tm, sv);
                        }
                }
                tm = fmaxf(tm, __shfl_xor(tm, 16));
                tm = fmaxf(tm, __shfl_xor(tm, 32));
                const bool skip = __all(tm <= mr + 7.0f);
                if (!skip) {
                    const float mnew  = fmaxf(mr, tm);
                    const float alpha = exp2f(mr - mnew);
                    mr = mnew;
                    #pragma unroll
                    for (int di = 0; di < 4; ++di)
                        #pragma unroll
                        for (int rg = 0; rg < 4; ++rg)
                            oT[di][rg] *= alpha;
                    lacc[0] *= alpha;
                }
                if (allv) {
                    #pragma unroll
                    for (int ni = 0; ni < 4; ++ni)
                        #pragma unroll
                        for (int rg = 0; rg < 4; ++rg)
                            pf[ni >> 1][((ni & 1) << 2) | rg] =
                                (__bf16)exp2f(st[ni][rg] - mr);
                } else {
                    #pragma unroll
                    for (int ni = 0; ni < 4; ++ni)
                        #pragma unroll
                        for (int rg = 0; rg < 4; ++rg) {
                            const float sv = st[ni][rg];
                            const float pv = (sv > -1.0e29f) ? exp2f(sv - mr) : 0.f;
                            pf[ni >> 1][((ni & 1) << 2) | rg] = (__bf16)pv;
                        }
                }
            }

            // ---- l-sum + O^T += V^T . P^T ----
            __builtin_amdgcn_s_setprio(1);
            lacc = __builtin_amdgcn_mfma_f32_16x16x32_bf16(onesf, pf[0], lacc, 0, 0, 0);
            lacc = __builtin_amdgcn_mfma_f32_16x16x32_bf16(onesf, pf[1], lacc, 0, 0, 0);
            #pragma unroll
            for (int di = 0; di < 4; ++di)
                #pragma unroll
                for (int kk = 0; kk < 2; ++kk) {
                    const bf16x8 vfr = *(const bf16x8*)&Vts[(di * 16 + c16) * 72 + kk * 32 + g8];
                    oT[di] = __builtin_amdgcn_mfma_f32_16x16x32_bf16(vfr, pf[kk], oT[di], 0, 0, 0);
                }
            __builtin_amdgcn_s_setprio(0);
        }

        // ---- epilogue: f32x4 stores ----
        const float inv = (lacc[0] > 0.f) ? 1.f / lacc[0] : 0.f;
        const int q = q0 + w16 + c16;
        #pragma unroll
        for (int di = 0; di < 4; ++di) {
            f32x4 ov;
            #pragma unroll
            for (int rg = 0; rg < 4; ++rg) ov[rg] = oT[di][rg] * inv;
            *(f32x4*)&out[((size_t)(b * M_ + q) * H_ + h) * 64 + di * 16 + g4] = ov;
        }
    }
}

// ---------------------------------------------------------------------------
extern "C" void kernel_launch(void* const* d_in, const int* in_sizes, int n_in,
                              void* d_out, int out_size, void* d_ws, size_t ws_size,
                              hipStream_t stream)
{
    const float* Pq = (const float*)d_in[0];
    const float* Pk = (const float*)d_in[1];
    const float* Pv = (const float*)d_in[2];
    const float* Vq = (const float*)d_in[3];
    const float* Vk = (const float*)d_in[4];
    const float* Vv = (const float*)d_in[5];
    const float* bq = (const float*)d_in[6];
    const float* bk = (const float*)d_in[7];
    const float* bv = (const float*)d_in[8];
    const int*   am = (const int*)d_in[9];
    const int*   pid = (const int*)d_in[10];
    float* out = (float*)d_out;

    // workspace: tab 1MB | VTb 192KB (@1MB) | Qb,Kb,Vt bf16 16MB each (@2MB)
    float* tab = (float*)d_ws;
    unsigned short* VTb = (unsigned short*)((char*)d_ws + (1 << 20));
    unsigned short* Qb  = (unsigned short*)((char*)d_ws + (2 << 20));
    unsigned short* Kb = Qb + (size_t)B_ * H_ * M_ * 64;
    unsigned short* Vt = Kb + (size_t)B_ * H_ * M_ * 64;

    prep_kernel<<<dim3((B_ * M_ * 16 + 98304) / 256), dim3(256), 0, stream>>>(
        pid, Vq, Vk, Vv, tab, VTb);

    qkv_proj_mfma_kernel<<<dim3(16, 64, 3), dim3(256), 0, stream>>>(
        Pq, Pk, Pv, VTb, bq, bk, bv, tab, Qb, Kb, Vt);

    flash_mfma_kernel<<<dim3(1024), dim3(256), 0, stream>>>(
        Qb, Kb, Vt, am, out);
}